// Round 13
// baseline (523.913 us; speedup 1.0000x reference)
//
#include <hip/hip_runtime.h>
#include <hip/hip_bf16.h>

// f32 in/out. All intermediates bf16 (f32 accumulation).
// Round-13 structure:
//  - Weights stored in MFMA-FRAGMENT ORDER in global (WB: frag-major, 16B/lane
//    coalesced). Round-11 lesson refined: global B-frags are fine IF the
//    layout is frag-order; the regression was the per-lane 256B stride.
//  - k_aggemm<DIN>: fused gather-aggregate + GEMM. Block=64 nodes; each wave
//    aggregates ITS OWN 16 nodes into a wave-private LDS A-tile, then MFMAs
//    those rows. Zero barriers, LDS <=17.4KB -> occupancy same as k_agg.
//    Deletes m1/m2 round-trips (115MB) + 2 dispatches.
//  - k_gemm3 / k_mlp: no weight LDS; k_mlp a1 LDS is wave-local (no barriers).
//  - Aggregation math bit-identical to round 9 (exact unpack+v_add_f32;
//    round-8 fdot2 rounding and round-10 pk_add both rejected by evidence).
//  - k_agg<128-dim gather> pinned at ~3.4TB/s L2-miss wall for 4 rounds ->
//    attack traffic around it, not the kernel.

typedef unsigned short u16;
typedef unsigned int   u32;
typedef __attribute__((ext_vector_type(8))) short short8;
typedef __attribute__((ext_vector_type(4))) float f32x4;

__device__ __forceinline__ float b2f(u16 u){
  union { u32 i; float f; } c; c.i = ((u32)u) << 16; return c.f;
}
__device__ __forceinline__ u16 f2b(float f){
  union { float f; u32 i; } c; c.f = f;
  u32 x = c.i;
  u32 r = x + 0x7FFFu + ((x >> 16) & 1u);   // round-to-nearest-even
  return (u16)(r >> 16);
}

// exact bf16-pair accumulate: a[0..7] += dims of uint4 (8 bf16)
__device__ __forceinline__ void acc8(uint4 u, float* a){
  a[0] += b2f((u16)(u.x & 0xffff)); a[1] += b2f((u16)(u.x >> 16));
  a[2] += b2f((u16)(u.y & 0xffff)); a[3] += b2f((u16)(u.y >> 16));
  a[4] += b2f((u16)(u.z & 0xffff)); a[5] += b2f((u16)(u.z >> 16));
  a[6] += b2f((u16)(u.w & 0xffff)); a[7] += b2f((u16)(u.w >> 16));
}

// fragment-order weight blocks (bf16). Entry ((nt*KS+ks)*64 + lane)*8 + j
// holds W[k= ks*32+(lane>>4)*8+j][n= nt*16+(lane&15)].
//   WB1 @0     : W1 (K=64 ,N=128) NT=8 KS=2 -> 8192
//   WB2 @8192  : W2 (K=128,N=128) NT=8 KS=4 -> 16384
//   WB3 @24576 : W3 (K=128,N=64 ) NT=4 KS=4 -> 8192
//   WB4 @32768 : P1 (K=128,N=64 ) NT=4 KS=4 -> 8192
//   WB5 @40960 : P2 (K=64 ,N=32 ) NT=2 KS=2 -> 2048   total 43008
#define NWT 43008

__device__ __forceinline__ float wb_src(int i, int KS, int N, const float* W){
  int frag = i >> 9, rem = i & 511;
  int lane = rem >> 3, j = rem & 7;
  int nt = frag / KS, ks = frag % KS;
  int n = nt*16 + (lane & 15);
  int k = ks*32 + (lane >> 4)*8 + j;
  return W[k*N + n];
}

// ---------------- hist (+ frag-order weight convert) ----------------

__global__ __launch_bounds__(256) void k_histK(const int* __restrict__ dst, int ne, int K,
    u32* __restrict__ bhist,
    const float* __restrict__ W1, const float* __restrict__ W2, const float* __restrict__ W3,
    const float* __restrict__ P1, const float* __restrict__ P2, u16* __restrict__ WB){
  extern __shared__ u32 sh[];
  int t = threadIdx.x;
  for (int i = blockIdx.x*256 + t; i < NWT; i += gridDim.x*256){
    float v;
    if (i < 8192)       v = wb_src(i,        2, 128, W1);
    else if (i < 24576) v = wb_src(i-8192,   4, 128, W2);
    else if (i < 32768) v = wb_src(i-24576,  4,  64, W3);
    else if (i < 40960) v = wb_src(i-32768,  4,  64, P1);
    else                v = wb_src(i-40960,  2,  32, P2);
    WB[i] = f2b(v);
  }
  for (int i = t; i < K; i += 256) sh[i] = 0;
  __syncthreads();
  for (int i = blockIdx.x*256 + t; i < ne; i += gridDim.x*256)
    atomicAdd(&sh[dst[i] >> 8], 1u);
  __syncthreads();
  int rot = (int)((blockIdx.x * 73u) % (u32)K);
  for (int jj = t; jj < K; jj += 256){
    int i = jj + rot; if (i >= K) i -= K;
    u32 v = sh[i];
    if (v) atomicAdd(&bhist[i], v);
  }
}

__global__ __launch_bounds__(256) void k_scanK(const u32* __restrict__ bhist, int K,
                                               u32* __restrict__ bbase, u32* __restrict__ gcur){
  __shared__ u32 s[256];
  int t = threadIdx.x;
  int items = (K + 255) / 256;
  u32 local[16];
  int s0 = t * items;
  u32 sum = 0;
  for (int j = 0; j < items; j++){
    int idx = s0 + j;
    u32 v = (idx < K) ? bhist[idx] : 0;
    local[j] = v; sum += v;
  }
  s[t] = sum; __syncthreads();
  for (int off = 1; off < 256; off <<= 1){
    u32 add = (t >= off) ? s[t-off] : 0;
    __syncthreads();
    s[t] += add;
    __syncthreads();
  }
  u32 run = s[t] - sum;
  for (int j = 0; j < items; j++){
    int idx = s0 + j;
    if (idx < K){ bbase[idx] = run; gcur[idx] = run; }
    run += local[j];
  }
  if (t == 255) bbase[K] = s[255];
}

__global__ __launch_bounds__(256) void k_scatterR(const int* __restrict__ src, const int* __restrict__ dst,
                                                  int ne, int K, u32* __restrict__ gcur,
                                                  u32* __restrict__ ebuf){
  extern __shared__ u32 cnt[];
  int t = threadIdx.x;
  int e0 = blockIdx.x * 4096;
  for (int i = t; i < K; i += 256) cnt[i] = 0;
  __syncthreads();
#pragma unroll
  for (int j = 0; j < 16; j++){
    int e = e0 + j*256 + t;
    if (e < ne) atomicAdd(&cnt[dst[e] >> 8], 1u);
  }
  __syncthreads();
  int rot = (int)((blockIdx.x * 73u) % (u32)K);
  for (int jj = t; jj < K; jj += 256){
    int i = jj + rot; if (i >= K) i -= K;
    u32 c = cnt[i];
    if (c) cnt[i] = atomicAdd(&gcur[i], c);
  }
  __syncthreads();
#pragma unroll
  for (int j = 0; j < 16; j++){
    int e = e0 + j*256 + t;
    if (e < ne){
      int d = dst[e];
      u32 p = atomicAdd(&cnt[d >> 8], 1u);
      ebuf[p] = ((u32)(d & 255) << 18) | (u32)src[e];
    }
  }
}

// one block per 256-node bucket: row_ptr + r + col; fused x0 = table*r (bf16)
__global__ __launch_bounds__(256) void k_csr(const u32* __restrict__ ebuf, const u32* __restrict__ bbase,
                                             int n, int ne, int* __restrict__ row_ptr,
                                             float* __restrict__ r, int* __restrict__ col,
                                             const float* __restrict__ ut, const float* __restrict__ it,
                                             int nu, u16* __restrict__ x0){
  __shared__ u32 cnt[256];
  __shared__ u32 pfx[256];
  __shared__ u32 cur[256];
  __shared__ float rsh[256];
  int b = blockIdx.x, t = threadIdx.x;
  u32 bb = bbase[b], be = bbase[b+1];
  int nbase = b << 8;
  int nn = n - nbase; if (nn > 256) nn = 256;
  cnt[t] = 0;
  __syncthreads();
  for (u32 e = bb + t; e < be; e += 256)
    atomicAdd(&cnt[ebuf[e] >> 18], 1u);
  __syncthreads();
  pfx[t] = cnt[t];
  __syncthreads();
  for (int off = 1; off < 256; off <<= 1){
    u32 add = (t >= off) ? pfx[t-off] : 0;
    __syncthreads();
    pfx[t] += add;
    __syncthreads();
  }
  u32 excl = pfx[t] - cnt[t];
  cur[t] = bb + excl;
  if (t < nn){
    float rv = rsqrtf(fmaxf((float)cnt[t], 1.0f));
    row_ptr[nbase + t] = (int)(bb + excl);
    r[nbase + t] = rv;
    rsh[t] = rv;
  }
  __syncthreads();
  for (u32 e = bb + t; e < be; e += 256){
    u32 v = ebuf[e];
    u32 p = atomicAdd(&cur[v >> 18], 1u);
    col[p] = (int)(v & 0x3FFFFu);
  }
  if (b == 0 && t == 0) row_ptr[n] = ne;
  for (int i = t; i < nn*16; i += 256){
    int ln = i >> 4;
    int node = nbase + ln;
    int c4 = (i & 15) << 2;
    float rv = rsh[ln];
    const float* srcp = (node < nu) ? (ut + (size_t)node*64 + c4)
                                    : (it + (size_t)(node-nu)*64 + c4);
    float4 v = *(const float4*)srcp;
    ushort4 o;
    o.x = f2b(v.x*rv); o.y = f2b(v.y*rv); o.z = f2b(v.z*rv); o.w = f2b(v.w*rv);
    *(ushort4*)(x0 + (size_t)node*64 + c4) = o;
  }
}

// ---------------- fused aggregate + GEMM (layers 1 and 2) ----------------
// Block = 64 nodes, 4 waves; wave aggregates its own 16 nodes into a
// wave-private LDS A-tile (stride DIN+8), then MFMAs those 16 rows vs WB
// (frag-order global, L2-hot). OUT=128 fixed. h = relu(m@W + b) * r.
// NO barriers: all LDS traffic is wave-local (in-order per wave).
template<int DIN>
__global__ __launch_bounds__(256) void k_aggemm(
    const u16* __restrict__ x, const float* __restrict__ r,
    const int* __restrict__ row_ptr, const int* __restrict__ col,
    const u16* __restrict__ WB, const float* __restrict__ bias,
    u16* __restrict__ C, int n)
{
  constexpr int G  = DIN/8;
  constexpr int E  = 64/G;
  constexpr int KP = DIN + 8;
  constexpr int KS = DIN/32;
  __shared__ u16 As[64*KP];
  const int t = threadIdx.x;
  const int wave = t >> 6, lane = t & 63;
  const int gidx = lane / G, l = lane % G;
  const int quad = lane >> 4, m16 = lane & 15;
  const int nodeb = blockIdx.x*64 + wave*16;

  // aggregate 16 nodes (bit-identical to k_agg round 9)
  for (int i = 0; i < 16; i++){
    int node = nodeb + i;
    float a[8] = {0.f,0.f,0.f,0.f,0.f,0.f,0.f,0.f};
    if (node < n){
      int beg = row_ptr[node], end = row_ptr[node+1];
      int e = beg + gidx;
      for (; e + E < end; e += 2*E){
        int s0 = col[e];
        int s1 = col[e+E];
        uint4 u0 = *(const uint4*)(x + (size_t)s0*DIN + l*8);
        uint4 u1 = *(const uint4*)(x + (size_t)s1*DIN + l*8);
        acc8(u0, a);
        acc8(u1, a);
      }
      if (e < end) acc8(*(const uint4*)(x + (size_t)col[e]*DIN + l*8), a);
    }
#pragma unroll
    for (int off = G; off < 64; off <<= 1){
#pragma unroll
      for (int j = 0; j < 8; j++) a[j] += __shfl_xor(a[j], off);
    }
    if (gidx == 0){
      float rn = (node < n) ? r[node] : 0.f;
      uint4 o;
      o.x = (u32)f2b(a[0]*rn) | ((u32)f2b(a[1]*rn) << 16);
      o.y = (u32)f2b(a[2]*rn) | ((u32)f2b(a[3]*rn) << 16);
      o.z = (u32)f2b(a[4]*rn) | ((u32)f2b(a[5]*rn) << 16);
      o.w = (u32)f2b(a[6]*rn) | ((u32)f2b(a[7]*rn) << 16);
      *(uint4*)(As + (size_t)(wave*16 + i)*KP + l*8) = o;
    }
  }

  // GEMM on this wave's 16 rows (wave-local LDS -> no barrier needed)
  short8 afr[KS];
#pragma unroll
  for (int ks = 0; ks < KS; ks++)
    afr[ks] = *(const short8*)(As + (size_t)(wave*16 + m16)*KP + ks*32 + quad*8);

  f32x4 acc[8];
#pragma unroll
  for (int nt = 0; nt < 8; nt++) acc[nt] = (f32x4){0.f,0.f,0.f,0.f};
#pragma unroll
  for (int nt = 0; nt < 8; nt++){
#pragma unroll
    for (int ks = 0; ks < KS; ks++){
      short8 b = *(const short8*)(WB + (size_t)((nt*KS + ks)*64 + lane)*8);
      acc[nt] = __builtin_amdgcn_mfma_f32_16x16x32_bf16(afr[ks], b, acc[nt], 0, 0, 0);
    }
  }

  float bv[8];
#pragma unroll
  for (int nt = 0; nt < 8; nt++) bv[nt] = bias[nt*16 + m16];
  int row0 = nodeb + quad*4;
#pragma unroll
  for (int reg = 0; reg < 4; reg++){
    int row = row0 + reg;
    if (row < n){
      float rs = r[row];
#pragma unroll
      for (int nt = 0; nt < 8; nt++){
        float v = fmaxf(acc[nt][reg] + bv[nt], 0.f) * rs;
        C[(size_t)row*128 + nt*16 + m16] = f2b(v);
      }
    }
  }
}

// ---------------- standalone aggregation (g3 -> x3, with bias) ----------------
template<int D, bool BIAS>
__global__ __launch_bounds__(256) void k_agg(const u16* __restrict__ x, const float* __restrict__ r,
    const int* __restrict__ row_ptr, const int* __restrict__ col,
    const float* __restrict__ bias, u16* __restrict__ out, int n){
  constexpr int G = D/8;
  constexpr int E = 64/G;
  int wid = (blockIdx.x*256 + threadIdx.x) >> 6;
  int lane = threadIdx.x & 63;
  if (wid >= n) return;
  int gidx = lane / G;
  int l    = lane % G;
  int beg = row_ptr[wid], end = row_ptr[wid+1];
  float a[8] = {0.f,0.f,0.f,0.f,0.f,0.f,0.f,0.f};
  int e = beg + gidx;
  for (; e + E < end; e += 2*E){
    int s0 = col[e];
    int s1 = col[e+E];
    uint4 u0 = *(const uint4*)(x + (size_t)s0*D + l*8);
    uint4 u1 = *(const uint4*)(x + (size_t)s1*D + l*8);
    acc8(u0, a);
    acc8(u1, a);
  }
  if (e < end){
    acc8(*(const uint4*)(x + (size_t)col[e]*D + l*8), a);
  }
#pragma unroll
  for (int off = G; off < 64; off <<= 1){
#pragma unroll
    for (int i = 0; i < 8; i++) a[i] += __shfl_xor(a[i], off);
  }
  if (gidx == 0){
    float rn = r[wid];
    float v[8];
#pragma unroll
    for (int i = 0; i < 8; i++){
      float y = a[i] * rn;
      if constexpr (BIAS) y += bias[l*8 + i];
      v[i] = y;
    }
    uint4 o;
    o.x = (u32)f2b(v[0]) | ((u32)f2b(v[1]) << 16);
    o.y = (u32)f2b(v[2]) | ((u32)f2b(v[3]) << 16);
    o.z = (u32)f2b(v[4]) | ((u32)f2b(v[5]) << 16);
    o.w = (u32)f2b(v[6]) | ((u32)f2b(v[7]) << 16);
    *(uint4*)(out + (size_t)wid*D + l*8) = o;
  }
}

// ---------------- GEMM3: g3[N,64] = h2[N,128] @ W3 (no bias/act) ----------------
// block 128 rows, wave 32 rows (2 m-tiles); A direct global; B frag-order global.
__global__ __launch_bounds__(256) void k_gemm3(
    const u16* __restrict__ A, const u16* __restrict__ WB, u16* __restrict__ C, int nrows)
{
  const int t = threadIdx.x;
  const int wave = t >> 6, lane = t & 63;
  const int quad = lane >> 4, m16 = lane & 15;
  const int rowb = blockIdx.x*128 + wave*32;

  const short8 zz = {0,0,0,0,0,0,0,0};
  short8 afr[2][4];
#pragma unroll
  for (int mt = 0; mt < 2; mt++){
    int row = rowb + mt*16 + m16;
    bool ok = row < nrows;
#pragma unroll
    for (int ks = 0; ks < 4; ks++)
      afr[mt][ks] = ok ? *(const short8*)(A + (size_t)row*128 + ks*32 + quad*8) : zz;
  }
  f32x4 acc[2][4];
#pragma unroll
  for (int mt = 0; mt < 2; mt++)
#pragma unroll
    for (int nt = 0; nt < 4; nt++) acc[mt][nt] = (f32x4){0.f,0.f,0.f,0.f};
#pragma unroll
  for (int nt = 0; nt < 4; nt++){
#pragma unroll
    for (int ks = 0; ks < 4; ks++){
      short8 b = *(const short8*)(WB + (size_t)((nt*4 + ks)*64 + lane)*8);
      acc[0][nt] = __builtin_amdgcn_mfma_f32_16x16x32_bf16(afr[0][ks], b, acc[0][nt], 0, 0, 0);
      acc[1][nt] = __builtin_amdgcn_mfma_f32_16x16x32_bf16(afr[1][ks], b, acc[1][nt], 0, 0, 0);
    }
  }
#pragma unroll
  for (int mt = 0; mt < 2; mt++){
    int row0 = rowb + mt*16 + quad*4;
#pragma unroll
    for (int reg = 0; reg < 4; reg++){
      int row = row0 + reg;
      if (row >= nrows) continue;
#pragma unroll
      for (int nt = 0; nt < 4; nt++)
        C[(size_t)row*64 + nt*16 + m16] = f2b(acc[mt][nt][reg]);
    }
  }
}

// ---------------- fused MLP: sigmoid(relu(relu(z P1+pb1) P2+pb2) . P3 + pb3) ----------------
// z = concat(x3[uidx], x3[nu+vidx]) as K=128 A-frags. B from WB4/WB5 frag-order
// global. a1 LDS round-trip is wave-local (rows wave*32..+31) -> no barriers.
__global__ __launch_bounds__(256) void k_mlp(
    const u16* __restrict__ x3, const u16* __restrict__ WB4, const float* __restrict__ pb1v,
    const u16* __restrict__ WB5, const float* __restrict__ pb2v,
    const float* __restrict__ P3, const float* __restrict__ pb3,
    const int* __restrict__ uidx, const int* __restrict__ vidx,
    int B, int nu, float* __restrict__ outp)
{
  __shared__ u16 a1[128*72];
  const int t = threadIdx.x;
  const int wave = t >> 6, lane = t & 63;
  const int quad = lane >> 4, m16 = lane & 15;
  const int rowb = blockIdx.x*128 + wave*32;

  const short8 zz = {0,0,0,0,0,0,0,0};
  short8 afr[2][4];
#pragma unroll
  for (int mt = 0; mt < 2; mt++){
    int row = rowb + mt*16 + m16;
    bool ok = row < B;
#pragma unroll
    for (int ks = 0; ks < 4; ks++){
      int k = ks*32 + quad*8;
      if (!ok){ afr[mt][ks] = zz; continue; }
      int node, kk;
      if (k < 64){ node = uidx[row];      kk = k; }
      else       { node = nu + vidx[row]; kk = k - 64; }
      afr[mt][ks] = *(const short8*)(x3 + (size_t)node*64 + kk);
    }
  }
  f32x4 acc[2][4];
#pragma unroll
  for (int mt = 0; mt < 2; mt++)
#pragma unroll
    for (int nt = 0; nt < 4; nt++) acc[mt][nt] = (f32x4){0.f,0.f,0.f,0.f};
#pragma unroll
  for (int nt = 0; nt < 4; nt++){
#pragma unroll
    for (int ks = 0; ks < 4; ks++){
      short8 b = *(const short8*)(WB4 + (size_t)((nt*4 + ks)*64 + lane)*8);
      acc[0][nt] = __builtin_amdgcn_mfma_f32_16x16x32_bf16(afr[0][ks], b, acc[0][nt], 0, 0, 0);
      acc[1][nt] = __builtin_amdgcn_mfma_f32_16x16x32_bf16(afr[1][ks], b, acc[1][nt], 0, 0, 0);
    }
  }
  float pb1s[4];
#pragma unroll
  for (int nt = 0; nt < 4; nt++) pb1s[nt] = pb1v[nt*16 + m16];
#pragma unroll
  for (int mt = 0; mt < 2; mt++){
    int rl0 = wave*32 + mt*16 + quad*4;
#pragma unroll
    for (int reg = 0; reg < 4; reg++){
#pragma unroll
      for (int nt = 0; nt < 4; nt++){
        float v = fmaxf(acc[mt][nt][reg] + pb1s[nt], 0.f);
        a1[(rl0 + reg)*72 + nt*16 + m16] = f2b(v);
      }
    }
  }
  // wave-local LDS: in-order per wave, no barrier needed
  short8 af2[2][2];
#pragma unroll
  for (int mt = 0; mt < 2; mt++){
    int rl = wave*32 + mt*16 + m16;
#pragma unroll
    for (int ks = 0; ks < 2; ks++)
      af2[mt][ks] = *(const short8*)(a1 + rl*72 + ks*32 + quad*8);
  }
  f32x4 acc2[2][2];
#pragma unroll
  for (int mt = 0; mt < 2; mt++)
#pragma unroll
    for (int nt = 0; nt < 2; nt++) acc2[mt][nt] = (f32x4){0.f,0.f,0.f,0.f};
#pragma unroll
  for (int nt = 0; nt < 2; nt++){
#pragma unroll
    for (int ks = 0; ks < 2; ks++){
      short8 b = *(const short8*)(WB5 + (size_t)((nt*2 + ks)*64 + lane)*8);
      acc2[0][nt] = __builtin_amdgcn_mfma_f32_16x16x32_bf16(af2[0][ks], b, acc2[0][nt], 0, 0, 0);
      acc2[1][nt] = __builtin_amdgcn_mfma_f32_16x16x32_bf16(af2[1][ks], b, acc2[1][nt], 0, 0, 0);
    }
  }
  float b0 = pb2v[m16], b1v = pb2v[16 + m16];
  float p0 = P3[m16],   p1 = P3[16 + m16];
  float pb = pb3[0];
#pragma unroll
  for (int mt = 0; mt < 2; mt++){
    float v4[4];
#pragma unroll
    for (int reg = 0; reg < 4; reg++){
      float part = fmaxf(acc2[mt][0][reg] + b0, 0.f) * p0
                 + fmaxf(acc2[mt][1][reg] + b1v, 0.f) * p1;
      part += __shfl_xor(part, 1);
      part += __shfl_xor(part, 2);
      part += __shfl_xor(part, 4);
      part += __shfl_xor(part, 8);
      v4[reg] = 1.f / (1.f + __expf(-(part + pb)));
    }
    if (m16 == 0){
      int row0 = rowb + mt*16 + quad*4;
      if (row0 + 3 < B){
        *(float4*)(outp + row0) = make_float4(v4[0], v4[1], v4[2], v4[3]);
      } else {
#pragma unroll
        for (int reg = 0; reg < 4; reg++)
          if (row0 + reg < B) outp[row0 + reg] = v4[reg];
      }
    }
  }
}

// ---------------- launcher ----------------

extern "C" void kernel_launch(void* const* d_in, const int* in_sizes, int n_in,
                              void* d_out, int out_size, void* d_ws, size_t ws_size,
                              hipStream_t stream){
  const float* ut  = (const float*)d_in[0];
  const float* it  = (const float*)d_in[1];
  const float* W1  = (const float*)d_in[2];
  const float* b1  = (const float*)d_in[3];
  const float* W2  = (const float*)d_in[4];
  const float* b2  = (const float*)d_in[5];
  const float* W3  = (const float*)d_in[6];
  const float* b3  = (const float*)d_in[7];
  const float* P1  = (const float*)d_in[8];
  const float* pb1 = (const float*)d_in[9];
  const float* P2  = (const float*)d_in[10];
  const float* pb2 = (const float*)d_in[11];
  const float* P3  = (const float*)d_in[12];
  const float* pb3 = (const float*)d_in[13];
  const int* src  = (const int*)d_in[14];
  const int* dst  = (const int*)d_in[15];
  const int* uidx = (const int*)d_in[16];
  const int* vidx = (const int*)d_in[17];

  const int NU = in_sizes[0] / 64;
  const int NI = in_sizes[1] / 64;
  const int N  = NU + NI;
  const int NE = in_sizes[14];
  const int B  = in_sizes[16];
  const int K  = (N + 255) >> 8;

  char* w = (char*)d_ws;
  auto alloc = [&](size_t bytes)->void*{
    void* p = (void*)w;
    w += (bytes + 255) & ~(size_t)255;
    return p;
  };
  float* r       = (float*)alloc((size_t)N*4);
  int*   row_ptr = (int*)  alloc((size_t)(N+1)*4);
  u32*   bhist   = (u32*)  alloc((size_t)K*4);
  u32*   bbase   = (u32*)  alloc((size_t)(K+1)*4);
  u32*   gcur    = (u32*)  alloc((size_t)K*4);
  int*   col     = (int*)  alloc((size_t)NE*4);
  u16*   Wall    = (u16*)  alloc((size_t)NWT*2);
  char*  bufE    = (char*) alloc((size_t)N*64*2 > (size_t)NE*4 ? (size_t)N*64*2 : (size_t)NE*4);
                                                      // ebuf(u32,NE) -> x3(bf16)
  char*  bufF    = (char*) alloc((size_t)N*128*2);    // h2(bf16)
  u16*   bufC    = (u16*)  alloc((size_t)N*128*2);    // h1(bf16)
  u16*   bufD    = (u16*)  alloc((size_t)N*64*2);     // x0 -> g3
  if ((size_t)(w - (char*)d_ws) > ws_size) return;

  u16* WB1 = Wall;            // frag-order W1
  u16* WB2 = Wall + 8192;
  u16* WB3 = Wall + 24576;
  u16* WB4 = Wall + 32768;
  u16* WB5 = Wall + 40960;

  u32* ebuf = (u32*)bufE;
  u16* x0   = bufD;

  hipMemsetAsync(bhist, 0, (size_t)K*4, stream);

  int g;
  k_histK  <<<128, 256, (size_t)K*4, stream>>>(dst, NE, K, bhist, W1, W2, W3, P1, P2, Wall);
  k_scanK  <<<1, 256, 0, stream>>>(bhist, K, bbase, gcur);
  g = (NE + 4095)/4096;
  k_scatterR<<<g, 256, (size_t)K*4, stream>>>(src, dst, NE, K, gcur, ebuf);
  k_csr    <<<K, 256, 0, stream>>>(ebuf, bbase, N, NE, row_ptr, r, col, ut, it, NU, x0);

  const int gA  = (N + 63)/64;    // aggemm blocks (64 nodes each)
  const int ga  = (N + 3)/4;      // standalone agg (4 nodes/block)
  const int gN  = (N + 127)/128;  // gemm3
  const int gB  = (B + 127)/128;  // mlp

  u16* h1 = bufC;
  k_aggemm<64><<<gA,256,0,stream>>>(x0, r, row_ptr, col, WB1, b1, h1, N);

  u16* h2 = (u16*)bufF;
  k_aggemm<128><<<gA,256,0,stream>>>(h1, r, row_ptr, col, WB2, b2, h2, N);

  u16* g3 = bufD;                 // x0 dead after aggemm1
  k_gemm3<<<gN,256,0,stream>>>(h2, WB3, g3, N);

  u16* x3 = (u16*)bufE;           // ebuf dead after k_csr
  k_agg<64,true><<<ga,256,0,stream>>>(g3, r, row_ptr, col, b3, x3, N);

  k_mlp<<<gB,256,0,stream>>>(x3, WB4, pb1, WB5, pb2, P3, pb3, uidx, vidx, B, NU, (float*)d_out);
}

// Round 15
// 513.275 us; speedup vs baseline: 1.0207x; 1.0207x over previous
//
#include <hip/hip_runtime.h>
#include <hip/hip_bf16.h>

// f32 in/out. All intermediates bf16 (f32 accumulation). Round-12 structure
// (best: 487.5us) + non-temporal hints on streaming traffic (round-15; round
// 14 failed to compile: NT store needs a native ext_vector_type, not HIP's
// uint4 class -> u32x4). Round-13 lesson: agg+GEMM fusion halves occupancy
// (74->44%) and gather concurrency -- the 115MB m1/m2 round-trip (~19us at
// stream BW) is cheaper. GEMMs = MFMA 16x16x32_bf16, weights pre-transposed
// (WT[n][K]) by k_histK, staged to padded LDS via coalesced 16B copies
// (round-11: direct global B-frags = strided L2 disaster). k_mlp fuses
// P1..sigmoid. k_csr emits x0. Aggs = exact unpack+v_add_f32 (round-8 fdot2
// rejected, round-10 pk_add neutral). NT hints: col loads + agg out stores +
// GEMM A loads are single-use streams polluting the 4MB/XCD L2 that holds the
// 38.4MB gather table (FETCH 250MB vs table = only ~60% reuse captured).

typedef unsigned short u16;
typedef unsigned int   u32;
typedef __attribute__((ext_vector_type(8))) short short8;
typedef __attribute__((ext_vector_type(4))) float f32x4;
typedef __attribute__((ext_vector_type(4))) unsigned int u32x4;

__device__ __forceinline__ float b2f(u16 u){
  union { u32 i; float f; } c; c.i = ((u32)u) << 16; return c.f;
}
__device__ __forceinline__ u16 f2b(float f){
  union { float f; u32 i; } c; c.f = f;
  u32 x = c.i;
  u32 r = x + 0x7FFFu + ((x >> 16) & 1u);   // round-to-nearest-even
  return (u16)(r >> 16);
}

// exact bf16-pair accumulate: a[0..7] += dims of uint4 (8 bf16)
__device__ __forceinline__ void acc8(uint4 u, float* a){
  a[0] += b2f((u16)(u.x & 0xffff)); a[1] += b2f((u16)(u.x >> 16));
  a[2] += b2f((u16)(u.y & 0xffff)); a[3] += b2f((u16)(u.y >> 16));
  a[4] += b2f((u16)(u.z & 0xffff)); a[5] += b2f((u16)(u.z >> 16));
  a[6] += b2f((u16)(u.w & 0xffff)); a[7] += b2f((u16)(u.w >> 16));
}

// weight layout (bf16, transposed WT[n*K+k]):
//   WT1 @0     : 128x64   (W1)
//   WT2 @8192  : 128x128  (W2)
//   WT3 @24576 : 64x128   (W3)
//   WT4 @32768 : 64x128   (P1)
//   WT5 @40960 : 32x64    (P2)   total 43008 u16
#define NWT 43008

// ---------------- hist (+ weight transpose-convert) ----------------

__global__ __launch_bounds__(256) void k_histK(const int* __restrict__ dst, int ne, int K,
    u32* __restrict__ bhist,
    const float* __restrict__ W1, const float* __restrict__ W2, const float* __restrict__ W3,
    const float* __restrict__ P1, const float* __restrict__ P2, u16* __restrict__ WT){
  extern __shared__ u32 sh[];
  int t = threadIdx.x;
  for (int i = blockIdx.x*256 + t; i < NWT; i += gridDim.x*256){
    float v;
    if (i < 8192)      { int j=i;        v = W1[(j%64)*128 + j/64];   }
    else if (i < 24576){ int j=i-8192;   v = W2[(j%128)*128 + j/128]; }
    else if (i < 32768){ int j=i-24576;  v = W3[(j%128)*64 + j/128];  }
    else if (i < 40960){ int j=i-32768;  v = P1[(j%128)*64 + j/128];  }
    else               { int j=i-40960;  v = P2[(j%64)*32 + j/64];    }
    WT[i] = f2b(v);
  }
  for (int i = t; i < K; i += 256) sh[i] = 0;
  __syncthreads();
  for (int i = blockIdx.x*256 + t; i < ne; i += gridDim.x*256)
    atomicAdd(&sh[dst[i] >> 8], 1u);
  __syncthreads();
  int rot = (int)((blockIdx.x * 73u) % (u32)K);
  for (int jj = t; jj < K; jj += 256){
    int i = jj + rot; if (i >= K) i -= K;
    u32 v = sh[i];
    if (v) atomicAdd(&bhist[i], v);
  }
}

__global__ __launch_bounds__(256) void k_scanK(const u32* __restrict__ bhist, int K,
                                               u32* __restrict__ bbase, u32* __restrict__ gcur){
  __shared__ u32 s[256];
  int t = threadIdx.x;
  int items = (K + 255) / 256;
  u32 local[16];
  int s0 = t * items;
  u32 sum = 0;
  for (int j = 0; j < items; j++){
    int idx = s0 + j;
    u32 v = (idx < K) ? bhist[idx] : 0;
    local[j] = v; sum += v;
  }
  s[t] = sum; __syncthreads();
  for (int off = 1; off < 256; off <<= 1){
    u32 add = (t >= off) ? s[t-off] : 0;
    __syncthreads();
    s[t] += add;
    __syncthreads();
  }
  u32 run = s[t] - sum;
  for (int j = 0; j < items; j++){
    int idx = s0 + j;
    if (idx < K){ bbase[idx] = run; gcur[idx] = run; }
    run += local[j];
  }
  if (t == 255) bbase[K] = s[255];
}

__global__ __launch_bounds__(256) void k_scatterR(const int* __restrict__ src, const int* __restrict__ dst,
                                                  int ne, int K, u32* __restrict__ gcur,
                                                  u32* __restrict__ ebuf){
  extern __shared__ u32 cnt[];
  int t = threadIdx.x;
  int e0 = blockIdx.x * 4096;
  for (int i = t; i < K; i += 256) cnt[i] = 0;
  __syncthreads();
#pragma unroll
  for (int j = 0; j < 16; j++){
    int e = e0 + j*256 + t;
    if (e < ne) atomicAdd(&cnt[dst[e] >> 8], 1u);
  }
  __syncthreads();
  int rot = (int)((blockIdx.x * 73u) % (u32)K);
  for (int jj = t; jj < K; jj += 256){
    int i = jj + rot; if (i >= K) i -= K;
    u32 c = cnt[i];
    if (c) cnt[i] = atomicAdd(&gcur[i], c);
  }
  __syncthreads();
#pragma unroll
  for (int j = 0; j < 16; j++){
    int e = e0 + j*256 + t;
    if (e < ne){
      int d = dst[e];
      u32 p = atomicAdd(&cnt[d >> 8], 1u);
      ebuf[p] = ((u32)(d & 255) << 18) | (u32)src[e];
    }
  }
}

// one block per 256-node bucket: row_ptr + r + col; fused x0 = table*r (bf16)
__global__ __launch_bounds__(256) void k_csr(const u32* __restrict__ ebuf, const u32* __restrict__ bbase,
                                             int n, int ne, int* __restrict__ row_ptr,
                                             float* __restrict__ r, int* __restrict__ col,
                                             const float* __restrict__ ut, const float* __restrict__ it,
                                             int nu, u16* __restrict__ x0){
  __shared__ u32 cnt[256];
  __shared__ u32 pfx[256];
  __shared__ u32 cur[256];
  __shared__ float rsh[256];
  int b = blockIdx.x, t = threadIdx.x;
  u32 bb = bbase[b], be = bbase[b+1];
  int nbase = b << 8;
  int nn = n - nbase; if (nn > 256) nn = 256;
  cnt[t] = 0;
  __syncthreads();
  for (u32 e = bb + t; e < be; e += 256)
    atomicAdd(&cnt[ebuf[e] >> 18], 1u);
  __syncthreads();
  pfx[t] = cnt[t];
  __syncthreads();
  for (int off = 1; off < 256; off <<= 1){
    u32 add = (t >= off) ? pfx[t-off] : 0;
    __syncthreads();
    pfx[t] += add;
    __syncthreads();
  }
  u32 excl = pfx[t] - cnt[t];
  cur[t] = bb + excl;
  if (t < nn){
    float rv = rsqrtf(fmaxf((float)cnt[t], 1.0f));
    row_ptr[nbase + t] = (int)(bb + excl);
    r[nbase + t] = rv;
    rsh[t] = rv;
  }
  __syncthreads();
  for (u32 e = bb + t; e < be; e += 256){
    u32 v = ebuf[e];
    u32 p = atomicAdd(&cur[v >> 18], 1u);
    col[p] = (int)(v & 0x3FFFFu);
  }
  if (b == 0 && t == 0) row_ptr[n] = ne;
  for (int i = t; i < nn*16; i += 256){
    int ln = i >> 4;
    int node = nbase + ln;
    int c4 = (i & 15) << 2;
    float rv = rsh[ln];
    const float* srcp = (node < nu) ? (ut + (size_t)node*64 + c4)
                                    : (it + (size_t)(node-nu)*64 + c4);
    float4 v = *(const float4*)srcp;
    ushort4 o;
    o.x = f2b(v.x*rv); o.y = f2b(v.y*rv); o.z = f2b(v.z*rv); o.w = f2b(v.w*rv);
    *(ushort4*)(x0 + (size_t)node*64 + c4) = o;
  }
}

// ---------------- aggregation: one wave per node, G-lane edge groups ----------------
// G = D/8 lanes per edge (uint4 = 8 bf16). E = 64/G edge groups; 2-edge unroll.
// NT hints: col loads + out stores are single-use streams -> keep out of L2.
template<int D, bool BIAS>
__global__ __launch_bounds__(256) void k_agg(const u16* __restrict__ x, const float* __restrict__ r,
    const int* __restrict__ row_ptr, const int* __restrict__ col,
    const float* __restrict__ bias, u16* __restrict__ out, int n){
  constexpr int G = D/8;
  constexpr int E = 64/G;
  int wid = (blockIdx.x*256 + threadIdx.x) >> 6;
  int lane = threadIdx.x & 63;
  if (wid >= n) return;
  int gidx = lane / G;
  int l    = lane % G;
  int beg = row_ptr[wid], end = row_ptr[wid+1];
  float a[8] = {0.f,0.f,0.f,0.f,0.f,0.f,0.f,0.f};
  int e = beg + gidx;
  for (; e + E < end; e += 2*E){
    int s0 = __builtin_nontemporal_load(col + e);
    int s1 = __builtin_nontemporal_load(col + e + E);
    uint4 u0 = *(const uint4*)(x + (size_t)s0*D + l*8);
    uint4 u1 = *(const uint4*)(x + (size_t)s1*D + l*8);
    acc8(u0, a);
    acc8(u1, a);
  }
  if (e < end){
    int s = __builtin_nontemporal_load(col + e);
    acc8(*(const uint4*)(x + (size_t)s*D + l*8), a);
  }
#pragma unroll
  for (int off = G; off < 64; off <<= 1){
#pragma unroll
    for (int i = 0; i < 8; i++) a[i] += __shfl_xor(a[i], off);
  }
  if (gidx == 0){
    float rn = r[wid];
    float v[8];
#pragma unroll
    for (int i = 0; i < 8; i++){
      float y = a[i] * rn;
      if constexpr (BIAS) y += bias[l*8 + i];
      v[i] = y;
    }
    u32x4 o;
    o.x = (u32)f2b(v[0]) | ((u32)f2b(v[1]) << 16);
    o.y = (u32)f2b(v[2]) | ((u32)f2b(v[3]) << 16);
    o.z = (u32)f2b(v[4]) | ((u32)f2b(v[5]) << 16);
    o.w = (u32)f2b(v[6]) | ((u32)f2b(v[7]) << 16);
    __builtin_nontemporal_store(o, (u32x4*)(out + (size_t)wid*D + l*8));
  }
}

// ---------------- MFMA GEMM: C[nrows,OUT] = act(A[nrows,K_] @ W + b) * r ----------------
// 256 thr = 4 waves x 32 rows (2 m-tiles), block 128 rows. A bf16 row-major,
// NT global->VGPR A-frags (single-use stream). WT staged into padded LDS
// (stride K_+8) via coalesced 16B copy.
template<int K_, int OUT, bool BIAS, bool RELU, bool SCALE>
__global__ __launch_bounds__(256) void k_mgemm(
    const u16* __restrict__ A, const u16* __restrict__ WT, const float* __restrict__ bias,
    const float* __restrict__ rr, u16* __restrict__ C, int nrows)
{
  constexpr int KP = K_ + 8;
  constexpr int NT = OUT / 16;
  constexpr int KS = K_ / 32;
  constexpr int KC = K_ / 8;          // 16B chunks per row
  __shared__ u16 Ws[OUT * KP];
  const int t = threadIdx.x;

  for (int i = t; i < OUT*KC; i += 256){
    int n = i / KC, kc = (i % KC) * 8;
    *(short8*)(Ws + n*KP + kc) = *(const short8*)(WT + (size_t)n*K_ + kc);
  }
  __syncthreads();

  const int wave = t >> 6, lane = t & 63;
  const int quad = lane >> 4, m16 = lane & 15;
  const int rowb = blockIdx.x*128 + wave*32;

  const short8 zz = {0,0,0,0,0,0,0,0};
  short8 afr[2][KS];
#pragma unroll
  for (int mt = 0; mt < 2; mt++){
    int row = rowb + mt*16 + m16;
    bool ok = row < nrows;
#pragma unroll
    for (int ks = 0; ks < KS; ks++){
      afr[mt][ks] = ok ? __builtin_nontemporal_load((const short8*)(A + (size_t)row*K_ + ks*32 + quad*8)) : zz;
    }
  }

  f32x4 acc[2][NT];
#pragma unroll
  for (int mt = 0; mt < 2; mt++)
#pragma unroll
    for (int nt = 0; nt < NT; nt++) acc[mt][nt] = (f32x4){0.f,0.f,0.f,0.f};

#pragma unroll
  for (int nt = 0; nt < NT; nt++){
#pragma unroll
    for (int ks = 0; ks < KS; ks++){
      short8 b = *(const short8*)(Ws + (size_t)(nt*16 + m16)*KP + ks*32 + quad*8);
      acc[0][nt] = __builtin_amdgcn_mfma_f32_16x16x32_bf16(afr[0][ks], b, acc[0][nt], 0, 0, 0);
      acc[1][nt] = __builtin_amdgcn_mfma_f32_16x16x32_bf16(afr[1][ks], b, acc[1][nt], 0, 0, 0);
    }
  }

  float bv[NT];
#pragma unroll
  for (int nt = 0; nt < NT; nt++){
    if constexpr (BIAS) bv[nt] = bias[nt*16 + m16]; else bv[nt] = 0.f;
  }
#pragma unroll
  for (int mt = 0; mt < 2; mt++){
    int row0 = rowb + mt*16 + quad*4;
#pragma unroll
    for (int reg = 0; reg < 4; reg++){
      int row = row0 + reg;
      if (row >= nrows) continue;
      float rs = 1.f;
      if constexpr (SCALE) rs = rr[row];
#pragma unroll
      for (int nt = 0; nt < NT; nt++){
        float v = acc[mt][nt][reg];
        if constexpr (BIAS) v += bv[nt];
        if constexpr (RELU) v = fmaxf(v, 0.f);
        if constexpr (SCALE) v *= rs;
        C[(size_t)row*OUT + nt*16 + m16] = f2b(v);
      }
    }
  }
}

// ---------------- fused MLP: sigmoid(relu(relu(z P1+pb1) P2+pb2) . P3 + pb3) ----------------
__global__ __launch_bounds__(256) void k_mlp(
    const u16* __restrict__ x3, const u16* __restrict__ WT4, const float* __restrict__ pb1v,
    const u16* __restrict__ WT5, const float* __restrict__ pb2v,
    const float* __restrict__ P3, const float* __restrict__ pb3,
    const int* __restrict__ uidx, const int* __restrict__ vidx,
    int B, int nu, float* __restrict__ outp)
{
  __shared__ u16 Ws4[64*136];
  __shared__ u16 Ws5[32*72];
  __shared__ u16 a1[128*72];
  const int t = threadIdx.x;
  const int wave = t >> 6, lane = t & 63;
  const int quad = lane >> 4, m16 = lane & 15;
  const int rowb = blockIdx.x*128 + wave*32;

  for (int i = t; i < 64*16; i += 256){
    int n = i >> 4, kc = (i & 15) * 8;
    *(short8*)(Ws4 + n*136 + kc) = *(const short8*)(WT4 + (size_t)n*128 + kc);
  }
  for (int i = t; i < 32*8; i += 256){
    int n = i >> 3, kc = (i & 7) * 8;
    *(short8*)(Ws5 + n*72 + kc) = *(const short8*)(WT5 + (size_t)n*64 + kc);
  }
  __syncthreads();

  // stage 1: K=128 gathered A, OUT=64
  const short8 zz = {0,0,0,0,0,0,0,0};
  short8 afr[2][4];
#pragma unroll
  for (int mt = 0; mt < 2; mt++){
    int row = rowb + mt*16 + m16;
    bool ok = row < B;
#pragma unroll
    for (int ks = 0; ks < 4; ks++){
      int k = ks*32 + quad*8;
      if (!ok){ afr[mt][ks] = zz; continue; }
      int node, kk;
      if (k < 64){ node = uidx[row];      kk = k; }
      else       { node = nu + vidx[row]; kk = k - 64; }
      afr[mt][ks] = *(const short8*)(x3 + (size_t)node*64 + kk);
    }
  }
  f32x4 acc[2][4];
#pragma unroll
  for (int mt = 0; mt < 2; mt++)
#pragma unroll
    for (int nt = 0; nt < 4; nt++) acc[mt][nt] = (f32x4){0.f,0.f,0.f,0.f};
#pragma unroll
  for (int nt = 0; nt < 4; nt++){
#pragma unroll
    for (int ks = 0; ks < 4; ks++){
      short8 b = *(const short8*)(Ws4 + (size_t)(nt*16 + m16)*136 + ks*32 + quad*8);
      acc[0][nt] = __builtin_amdgcn_mfma_f32_16x16x32_bf16(afr[0][ks], b, acc[0][nt], 0, 0, 0);
      acc[1][nt] = __builtin_amdgcn_mfma_f32_16x16x32_bf16(afr[1][ks], b, acc[1][nt], 0, 0, 0);
    }
  }
  float pb1s[4];
#pragma unroll
  for (int nt = 0; nt < 4; nt++) pb1s[nt] = pb1v[nt*16 + m16];
#pragma unroll
  for (int mt = 0; mt < 2; mt++){
    int rl0 = wave*32 + mt*16 + quad*4;
#pragma unroll
    for (int reg = 0; reg < 4; reg++){
#pragma unroll
      for (int nt = 0; nt < 4; nt++){
        float v = fmaxf(acc[mt][nt][reg] + pb1s[nt], 0.f);
        a1[(rl0 + reg)*72 + nt*16 + m16] = f2b(v);
      }
    }
  }
  __syncthreads();

  // stage 2: A from LDS, K=64, OUT=32
  short8 af2[2][2];
#pragma unroll
  for (int mt = 0; mt < 2; mt++){
    int rl = wave*32 + mt*16 + m16;
#pragma unroll
    for (int ks = 0; ks < 2; ks++)
      af2[mt][ks] = *(const short8*)(a1 + rl*72 + ks*32 + quad*8);
  }
  f32x4 acc2[2][2];
#pragma unroll
  for (int mt = 0; mt < 2; mt++)
#pragma unroll
    for (int nt = 0; nt < 2; nt++) acc2[mt][nt] = (f32x4){0.f,0.f,0.f,0.f};
#pragma unroll
  for (int nt = 0; nt < 2; nt++){
#pragma unroll
    for (int ks = 0; ks < 2; ks++){
      short8 b = *(const short8*)(Ws5 + (size_t)(nt*16 + m16)*72 + ks*32 + quad*8);
      acc2[0][nt] = __builtin_amdgcn_mfma_f32_16x16x32_bf16(af2[0][ks], b, acc2[0][nt], 0, 0, 0);
      acc2[1][nt] = __builtin_amdgcn_mfma_f32_16x16x32_bf16(af2[1][ks], b, acc2[1][nt], 0, 0, 0);
    }
  }
  float b0 = pb2v[m16], b1v = pb2v[16 + m16];
  float p0 = P3[m16],   p1 = P3[16 + m16];
  float pb = pb3[0];
#pragma unroll
  for (int mt = 0; mt < 2; mt++){
    float v4[4];
#pragma unroll
    for (int reg = 0; reg < 4; reg++){
      float part = fmaxf(acc2[mt][0][reg] + b0, 0.f) * p0
                 + fmaxf(acc2[mt][1][reg] + b1v, 0.f) * p1;
      part += __shfl_xor(part, 1);
      part += __shfl_xor(part, 2);
      part += __shfl_xor(part, 4);
      part += __shfl_xor(part, 8);
      v4[reg] = 1.f / (1.f + __expf(-(part + pb)));
    }
    if (m16 == 0){
      int row0 = rowb + mt*16 + quad*4;
      if (row0 + 3 < B){
        *(float4*)(outp + row0) = make_float4(v4[0], v4[1], v4[2], v4[3]);
      } else {
#pragma unroll
        for (int reg = 0; reg < 4; reg++)
          if (row0 + reg < B) outp[row0 + reg] = v4[reg];
      }
    }
  }
}

// ---------------- launcher ----------------

extern "C" void kernel_launch(void* const* d_in, const int* in_sizes, int n_in,
                              void* d_out, int out_size, void* d_ws, size_t ws_size,
                              hipStream_t stream){
  const float* ut  = (const float*)d_in[0];
  const float* it  = (const float*)d_in[1];
  const float* W1  = (const float*)d_in[2];
  const float* b1  = (const float*)d_in[3];
  const float* W2  = (const float*)d_in[4];
  const float* b2  = (const float*)d_in[5];
  const float* W3  = (const float*)d_in[6];
  const float* b3  = (const float*)d_in[7];
  const float* P1  = (const float*)d_in[8];
  const float* pb1 = (const float*)d_in[9];
  const float* P2  = (const float*)d_in[10];
  const float* pb2 = (const float*)d_in[11];
  const float* P3  = (const float*)d_in[12];
  const float* pb3 = (const float*)d_in[13];
  const int* src  = (const int*)d_in[14];
  const int* dst  = (const int*)d_in[15];
  const int* uidx = (const int*)d_in[16];
  const int* vidx = (const int*)d_in[17];

  const int NU = in_sizes[0] / 64;
  const int NI = in_sizes[1] / 64;
  const int N  = NU + NI;
  const int NE = in_sizes[14];
  const int B  = in_sizes[16];
  const int K  = (N + 255) >> 8;

  char* w = (char*)d_ws;
  auto alloc = [&](size_t bytes)->void*{
    void* p = (void*)w;
    w += (bytes + 255) & ~(size_t)255;
    return p;
  };
  float* r       = (float*)alloc((size_t)N*4);
  int*   row_ptr = (int*)  alloc((size_t)(N+1)*4);
  u32*   bhist   = (u32*)  alloc((size_t)K*4);
  u32*   bbase   = (u32*)  alloc((size_t)(K+1)*4);
  u32*   gcur    = (u32*)  alloc((size_t)K*4);
  int*   col     = (int*)  alloc((size_t)NE*4);
  u16*   Wall    = (u16*)  alloc((size_t)NWT*2);
  char*  bufE    = (char*) alloc((size_t)N*64*2 > (size_t)NE*4 ? (size_t)N*64*2 : (size_t)NE*4);
                                                      // ebuf(u32,NE) -> m1(bf16) -> x3(bf16)
  char*  bufF    = (char*) alloc((size_t)N*128*2);    // m2(bf16)
  u16*   bufC    = (u16*)  alloc((size_t)N*128*2);    // h1 -> h2
  u16*   bufD    = (u16*)  alloc((size_t)N*64*2);     // x0 -> g3
  if ((size_t)(w - (char*)d_ws) > ws_size) return;

  u16* WT1 = Wall;            // 128x64
  u16* WT2 = Wall + 8192;     // 128x128
  u16* WT3 = Wall + 24576;    // 64x128
  u16* WT4 = Wall + 32768;    // 64x128 (P1)
  u16* WT5 = Wall + 40960;    // 32x64  (P2)

  u32* ebuf = (u32*)bufE;
  u16* x0   = bufD;

  hipMemsetAsync(bhist, 0, (size_t)K*4, stream);

  int g;
  k_histK  <<<128, 256, (size_t)K*4, stream>>>(dst, NE, K, bhist, W1, W2, W3, P1, P2, Wall);
  k_scanK  <<<1, 256, 0, stream>>>(bhist, K, bbase, gcur);
  g = (NE + 4095)/4096;
  k_scatterR<<<g, 256, (size_t)K*4, stream>>>(src, dst, NE, K, gcur, ebuf);
  k_csr    <<<K, 256, 0, stream>>>(ebuf, bbase, N, NE, row_ptr, r, col, ut, it, NU, x0);

  const int ga  = (N + 3)/4;
  const int gN  = (N + 127)/128;
  const int gB  = (B + 127)/128;

  u16* m1 = (u16*)bufE;               // ebuf dead after k_csr
  k_agg<64,false><<<ga,256,0,stream>>>(x0, r, row_ptr, col, nullptr, m1, N);
  u16* h1 = bufC;
  k_mgemm<64,128,true,true,true><<<gN,256,0,stream>>>(m1, WT1, b1, r, h1, N);

  u16* m2 = (u16*)bufF;
  k_agg<128,false><<<ga,256,0,stream>>>(h1, r, row_ptr, col, nullptr, m2, N);
  u16* h2 = bufC;                     // h1 dead after agg
  k_mgemm<128,128,true,true,true><<<gN,256,0,stream>>>(m2, WT2, b2, r, h2, N);

  u16* g3 = bufD;                     // x0 dead after first agg
  k_mgemm<128,64,false,false,false><<<gN,256,0,stream>>>(h2, WT3, nullptr, nullptr, g3, N);

  u16* x3 = (u16*)bufE;               // m1 dead after GEMM1
  k_agg<64,true><<<ga,256,0,stream>>>(g3, r, row_ptr, col, b3, x3, N);

  k_mlp<<<gB,256,0,stream>>>(x3, WT4, pb1, WT5, pb2, P3, pb3, uidx, vidx, B, NU, (float*)d_out);
}